// Round 3
// baseline (887.851 us; speedup 1.0000x reference)
//
#include <hip/hip_runtime.h>
#include <math.h>

#define B_ 16
#define NH_ 256                // K (channels)
#define NE_ 8192               // codebook size
#define ED_ 256
#define L_ 256                 // positions per sample
#define NCH 32                 // n-chunks -> grid.x
#define CHUNK 256              // codes per block
#define STRIDE_P (B_ * NCH * L_)   // 131072 per field; 6 fields = 786432 < 1048576
#define LOSS_IDX 1048576
#define IND_BASE 1048577
#define KLW 0.0005f
#define KC 16                  // k-chunk staged in LDS
#define LDW 260                // padded LDS row (floats); 1040B, 16B-aligned rows

// ---------------- Kernel 1: register-tiled SGEMM + fused reductions ----------
// grid (NCH, B), block 1024 = 32tx (p) x 32ty (n). Block tile 256n x 256p, K=256.
// Thread tile 8n x 8p. Partials per (b, chunk, p) written into d_out z_q region.
__global__ __launch_bounds__(1024, 4) void k1_gemm(
    const float* __restrict__ z, const float* __restrict__ pw,
    const float* __restrict__ pb, const float* __restrict__ gum,
    float* __restrict__ out)
{
    __shared__ __align__(16) float Wt[KC * LDW];  // Wt[k][n]
    __shared__ __align__(16) float Zt[KC * LDW];  // Zt[k][p]
    const int tid = threadIdx.x;
    const int tx = tid >> 5;          // 0..31 : p-group
    const int ty = tid & 31;          // 0..31 : n-group (lane%32 within wave-half)
    const int ch = blockIdx.x, b = blockIdx.y;
    const int nc0 = ch * CHUNK;

    // bias preload -> accumulator init (bias folded in)
    float acc[8][8];
    {
        const float4 p0 = *(const float4*)(pb + nc0 + ty * 4);
        const float4 p1 = *(const float4*)(pb + nc0 + 128 + ty * 4);
        const float pbv[8] = {p0.x, p0.y, p0.z, p0.w, p1.x, p1.y, p1.z, p1.w};
        #pragma unroll
        for (int i = 0; i < 8; ++i)
            #pragma unroll
            for (int j = 0; j < 8; ++j) acc[i][j] = pbv[i];
    }

    // staging address precompute
    const int wk4 = tid & 3, wn = tid >> 2;          // W: float4 along c, 4-row transpose write
    const float* wsrc = pw + (size_t)(nc0 + wn) * NH_ + wk4 * 4;
    const int zk = tid >> 6, zp4 = (tid & 63) * 4;   // Z: direct copy rows
    const float* zsrc = z + ((size_t)b * NH_ + zk) * L_ + zp4;
    float* zdst = &Zt[zk * LDW + zp4];

    float4 wv = *(const float4*)(wsrc);
    float4 zv = *(const float4*)(zsrc);

    for (int kc = 0; kc < NH_; kc += KC) {
        // write staged regs to LDS
        Wt[(wk4 * 4 + 0) * LDW + wn] = wv.x;
        Wt[(wk4 * 4 + 1) * LDW + wn] = wv.y;
        Wt[(wk4 * 4 + 2) * LDW + wn] = wv.z;
        Wt[(wk4 * 4 + 3) * LDW + wn] = wv.w;
        *(float4*)zdst = zv;
        __syncthreads();
        // prefetch next chunk (latency hides under FMA loop)
        if (kc + KC < NH_) {
            wv = *(const float4*)(wsrc + kc + KC);
            zv = *(const float4*)(zsrc + (size_t)(kc + KC) * L_);
        }
        #pragma unroll
        for (int k = 0; k < KC; ++k) {
            const float4 a0 = *(const float4*)&Wt[k * LDW + ty * 4];
            const float4 a1 = *(const float4*)&Wt[k * LDW + 128 + ty * 4];
            const float4 b0 = *(const float4*)&Zt[k * LDW + tx * 4];
            const float4 b1 = *(const float4*)&Zt[k * LDW + 128 + tx * 4];
            const float av[8] = {a0.x, a0.y, a0.z, a0.w, a1.x, a1.y, a1.z, a1.w};
            const float bv[8] = {b0.x, b0.y, b0.z, b0.w, b1.x, b1.y, b1.z, b1.w};
            #pragma unroll
            for (int i = 0; i < 8; ++i)
                #pragma unroll
                for (int j = 0; j < 8; ++j)
                    acc[i][j] = fmaf(av[i], bv[j], acc[i][j]);
        }
        __syncthreads();
    }

    // ---- epilogue: fold 8n per p, then shfl-reduce over 32 ty lanes ----
    const size_t gbase = ((size_t)b * NE_ + nc0) * L_;
    #pragma unroll
    for (int h = 0; h < 2; ++h) {                 // j-halves: p = h*128 + tx*4 + jj
        const int pbase = h * 128 + tx * 4;
        float dmax[4], smax[4], S[4], T[4];
        int didx[4], sidx[4];
        #pragma unroll
        for (int jj = 0; jj < 4; ++jj) {
            dmax[jj] = -INFINITY; smax[jj] = -INFINITY;
            S[jj] = 0.f; T[jj] = 0.f; didx[jj] = 0x7fffffff; sidx[jj] = 0x7fffffff;
        }
        #pragma unroll
        for (int i = 0; i < 8; ++i) {
            const int nl = (i < 4) ? (ty * 4 + i) : (128 + ty * 4 + i - 4);
            const int ng = nc0 + nl;
            const float4 g = *(const float4*)(gum + gbase + (size_t)nl * L_ + pbase);
            const float gg[4] = {g.x, g.y, g.z, g.w};
            #pragma unroll
            for (int jj = 0; jj < 4; ++jj) {
                const float l = acc[i][h * 4 + jj];
                if (l > dmax[jj] || (l == dmax[jj] && ng < didx[jj])) { dmax[jj] = l; didx[jj] = ng; }
                const float sv = l + gg[jj];
                if (sv > smax[jj] || (sv == smax[jj] && ng < sidx[jj])) { smax[jj] = sv; sidx[jj] = ng; }
                const float e = expf(l);
                S[jj] += e;
                T[jj] = fmaf(l, e, T[jj]);
            }
        }
        #pragma unroll
        for (int m = 1; m < 32; m <<= 1) {        // closed within 32-lane halves
            #pragma unroll
            for (int jj = 0; jj < 4; ++jj) {
                float ov = __shfl_xor(dmax[jj], m); int oi = __shfl_xor(didx[jj], m);
                if (ov > dmax[jj] || (ov == dmax[jj] && oi < didx[jj])) { dmax[jj] = ov; didx[jj] = oi; }
                ov = __shfl_xor(smax[jj], m); oi = __shfl_xor(sidx[jj], m);
                if (ov > smax[jj] || (ov == smax[jj] && oi < sidx[jj])) { smax[jj] = ov; sidx[jj] = oi; }
                S[jj] += __shfl_xor(S[jj], m);
                T[jj] += __shfl_xor(T[jj], m);
            }
        }
        if (ty == 0) {
            #pragma unroll
            for (int jj = 0; jj < 4; ++jj) {
                const int base = (b * NCH + ch) * L_ + pbase + jj;
                out[0 * STRIDE_P + base] = dmax[jj];
                out[1 * STRIDE_P + base] = __int_as_float(didx[jj]);
                out[2 * STRIDE_P + base] = smax[jj];
                out[3 * STRIDE_P + base] = __int_as_float(sidx[jj]);
                out[4 * STRIDE_P + base] = S[jj];
                out[5 * STRIDE_P + base] = T[jj];
            }
        }
    }
    if (ch == 0 && b == 0 && tid == 0) out[LOSS_IDX] = 0.f;   // zero for k2 atomics
}

// ---------------- Kernel 2: combine chunks + mask + select + KL --------------
// grid (B), block 256 (one thread per position).
__global__ __launch_bounds__(256) void k2_combine(
    const float* __restrict__ noise, float* __restrict__ out)
{
    const int p = threadIdx.x, b = blockIdx.x;
    float dmax = -INFINITY, smax = -INFINITY, S = 0.f, T = 0.f;
    int didx = 0, sidx = 0;
    for (int ch = 0; ch < NCH; ++ch) {          // ascending chunk = ascending code idx
        const int base = (b * NCH + ch) * L_ + p;
        float dm = out[0 * STRIDE_P + base];
        int   di = __float_as_int(out[1 * STRIDE_P + base]);
        float sm = out[2 * STRIDE_P + base];
        int   si = __float_as_int(out[3 * STRIDE_P + base]);
        S += out[4 * STRIDE_P + base];
        T += out[5 * STRIDE_P + base];
        if (dm > dmax) { dmax = dm; didx = di; }
        if (sm > smax) { smax = sm; sidx = si; }
    }

    // mask: rank of noise within row (stable argsort semantics)
    __shared__ float nz[256];
    nz[p] = noise[b * L_ + p];
    __syncthreads();
    const float myv = nz[p];
    int rank = 0;
    for (int j = 0; j < 256; ++j) {
        float v = nz[j];
        rank += (v < myv) || (v == myv && j < p);
    }
    const int sel = (rank >= 128) ? sidx : didx;   // mask=1 -> stochastic branch
    out[IND_BASE + b * L_ + p] = (float)sel;

    // KL to uniform: sum_n qy*log(qy*NE) = T/S - log S + log NE   (m=0 basis)
    float kl = T / S - logf(S) + logf((float)NE_);
    __shared__ float red[256];
    red[p] = kl;
    __syncthreads();
    for (int s = 128; s > 0; s >>= 1) {
        if (p < s) red[p] += red[p + s];
        __syncthreads();
    }
    if (p == 0) atomicAdd(&out[LOSS_IDX], (KLW / 4096.f) * red[0]);
}

// ---------------- Kernel 3: z_q gather from codebook -------------------------
// grid (32, B), block 256: thread = one p, 8 d's. float4 codebook gathers
// (L2/L3-hot, 8 MiB), fully coalesced stores.
__global__ __launch_bounds__(256) void k3_gather(
    const float* __restrict__ emb, float* __restrict__ out)
{
    const int p = threadIdx.x;
    const int dc = blockIdx.x, b = blockIdx.y;
    const int sel = (int)out[IND_BASE + b * L_ + p];
    const float* er = emb + (size_t)sel * ED_ + dc * 8;
    const float4 e0 = *(const float4*)(er);
    const float4 e1 = *(const float4*)(er + 4);
    const size_t ob = ((size_t)b * ED_ + dc * 8) * L_ + p;
    out[ob + 0 * L_] = e0.x; out[ob + 1 * L_] = e0.y;
    out[ob + 2 * L_] = e0.z; out[ob + 3 * L_] = e0.w;
    out[ob + 4 * L_] = e1.x; out[ob + 5 * L_] = e1.y;
    out[ob + 6 * L_] = e1.z; out[ob + 7 * L_] = e1.w;
}

extern "C" void kernel_launch(void* const* d_in, const int* in_sizes, int n_in,
                              void* d_out, int out_size, void* d_ws, size_t ws_size,
                              hipStream_t stream) {
    const float* z     = (const float*)d_in[0];
    const float* pw    = (const float*)d_in[1];
    const float* pb    = (const float*)d_in[2];
    const float* emb   = (const float*)d_in[3];
    const float* gum   = (const float*)d_in[4];
    const float* noise = (const float*)d_in[5];
    float* out = (float*)d_out;

    hipLaunchKernelGGL(k1_gemm, dim3(NCH, B_), dim3(1024), 0, stream, z, pw, pb, gum, out);
    hipLaunchKernelGGL(k2_combine, dim3(B_), dim3(256), 0, stream, noise, out);
    hipLaunchKernelGGL(k3_gather, dim3(32, B_), dim3(256), 0, stream, emb, out);
}

// Round 5
// 440.630 us; speedup vs baseline: 2.0150x; 2.0150x over previous
//
#include <hip/hip_runtime.h>
#include <math.h>

#define B_ 16
#define NH_ 256                // K (channels)
#define NE_ 8192               // codebook size
#define ED_ 256
#define L_ 256                 // positions per sample
#define NCH 32                 // n-chunks -> grid.x
#define CHUNK 256              // codes per n-chunk
#define STRIDE_P (B_ * NCH * L_)   // 131072 per field; 6 fields = 786432 < 1048576
#define LOSS_IDX 1048576
#define IND_BASE 1048577
#define KLW 0.0005f
#define KC 16                  // k-chunk staged in LDS
#define WLD 260                // Wt row stride (floats): 1040B, 16B-aligned
#define ZLD 132                // Zt row stride (floats): 528B, 16B-aligned

// ---------------- Kernel 1: register-tiled SGEMM + fused reductions ----------
// grid (NCH, 2, B), block 512 = 32ty(n) x 16tx(p). Block tile 256n x 128p.
// Thread tile 8n x 8p = 64 acc. waves_per_eu(2,4): min-2 => 256-VGPR budget,
// NO spill (round-3 failure mode: default 8-waves target capped VGPR at 64 and
// spilled all 64 accumulators -> 2.6 GB scratch traffic).
__global__ __launch_bounds__(512)
__attribute__((amdgpu_waves_per_eu(2, 4)))
void k1_gemm(
    const float* __restrict__ z, const float* __restrict__ pw,
    const float* __restrict__ pb, const float* __restrict__ gum,
    float* __restrict__ out)
{
    __shared__ __align__(16) float Wt[KC * WLD];  // Wt[k][n], 16.6 KB
    __shared__ __align__(16) float Zt[KC * ZLD];  // Zt[k][p],  8.4 KB
    const int tid = threadIdx.x;
    const int tx = tid >> 5;          // 0..15 : p-group (uniform within 32-lane half)
    const int ty = tid & 31;          // 0..31 : n-group
    const int ch = blockIdx.x, psl = blockIdx.y, b = blockIdx.z;
    const int nc0 = ch * CHUNK;
    const int pofs = psl * 128;       // global p offset of this block

    // bias folded into accumulator init
    float acc[8][8];
    {
        const float4 p0 = *(const float4*)(pb + nc0 + ty * 4);
        const float4 p1 = *(const float4*)(pb + nc0 + 128 + ty * 4);
        const float pbv[8] = {p0.x, p0.y, p0.z, p0.w, p1.x, p1.y, p1.z, p1.w};
        #pragma unroll
        for (int i = 0; i < 8; ++i)
            #pragma unroll
            for (int j = 0; j < 8; ++j) acc[i][j] = pbv[i];
    }

    // staging addresses
    const int wn = tid >> 1, wh = tid & 1;            // W: 256n x 16k, 8 floats/thread
    const float* wsrc = pw + (size_t)(nc0 + wn) * NH_ + wh * 8;
    const int zk = tid >> 5, zp4 = (tid & 31) * 4;    // Z: 16k x 128p, 1 float4/thread
    const float* zsrc = z + ((size_t)b * NH_ + zk) * L_ + pofs + zp4;
    float* zdst = &Zt[zk * ZLD + zp4];

    float4 wv0 = *(const float4*)(wsrc);
    float4 wv1 = *(const float4*)(wsrc + 4);
    float4 zv  = *(const float4*)(zsrc);

    for (int kc = 0; kc < NH_; kc += KC) {
        // write staged regs to LDS (W transposed: Wt[k][n])
        {
            const float wa[4] = {wv0.x, wv0.y, wv0.z, wv0.w};
            const float wb[4] = {wv1.x, wv1.y, wv1.z, wv1.w};
            #pragma unroll
            for (int q = 0; q < 4; ++q) {
                Wt[(wh * 8 + q) * WLD + wn]     = wa[q];
                Wt[(wh * 8 + 4 + q) * WLD + wn] = wb[q];
            }
        }
        *(float4*)zdst = zv;
        __syncthreads();
        // prefetch next chunk (hides under FMA loop)
        if (kc + KC < NH_) {
            wv0 = *(const float4*)(wsrc + kc + KC);
            wv1 = *(const float4*)(wsrc + kc + KC + 4);
            zv  = *(const float4*)(zsrc + (size_t)(kc + KC) * L_);
        }
        #pragma unroll
        for (int k = 0; k < KC; ++k) {
            const float4 a0 = *(const float4*)&Wt[k * WLD + ty * 4];
            const float4 a1 = *(const float4*)&Wt[k * WLD + 128 + ty * 4];
            const float4 b0 = *(const float4*)&Zt[k * ZLD + tx * 4];
            const float4 b1 = *(const float4*)&Zt[k * ZLD + 64 + tx * 4];
            const float av[8] = {a0.x, a0.y, a0.z, a0.w, a1.x, a1.y, a1.z, a1.w};
            const float bv[8] = {b0.x, b0.y, b0.z, b0.w, b1.x, b1.y, b1.z, b1.w};
            #pragma unroll
            for (int i = 0; i < 8; ++i)
                #pragma unroll
                for (int j = 0; j < 8; ++j)
                    acc[i][j] = fmaf(av[i], bv[j], acc[i][j]);
        }
        __syncthreads();
    }

    // ---- epilogue: gumbel + argmaxes + exp sums, shfl-reduce over 32 ty lanes
    const size_t gbase = ((size_t)b * NE_ + nc0) * L_;
    #pragma unroll
    for (int h = 0; h < 2; ++h) {                 // p-halves: p_local = h*64 + tx*4 + jj
        const int pl = h * 64 + tx * 4;
        float dmax[4], smax[4], S[4], T[4];
        int didx[4], sidx[4];
        #pragma unroll
        for (int jj = 0; jj < 4; ++jj) {
            dmax[jj] = -INFINITY; smax[jj] = -INFINITY;
            S[jj] = 0.f; T[jj] = 0.f; didx[jj] = 0x7fffffff; sidx[jj] = 0x7fffffff;
        }
        #pragma unroll
        for (int i = 0; i < 8; ++i) {
            const int nl = (i < 4) ? (ty * 4 + i) : (128 + ty * 4 + i - 4);
            const int ng = nc0 + nl;
            const float4 g = *(const float4*)(gum + gbase + (size_t)nl * L_ + pofs + pl);
            const float gg[4] = {g.x, g.y, g.z, g.w};
            #pragma unroll
            for (int jj = 0; jj < 4; ++jj) {
                const float l = acc[i][h * 4 + jj];
                if (l > dmax[jj] || (l == dmax[jj] && ng < didx[jj])) { dmax[jj] = l; didx[jj] = ng; }
                const float sv = l + gg[jj];
                if (sv > smax[jj] || (sv == smax[jj] && ng < sidx[jj])) { smax[jj] = sv; sidx[jj] = ng; }
                const float e = expf(l);
                S[jj] += e;
                T[jj] = fmaf(l, e, T[jj]);
            }
        }
        #pragma unroll
        for (int m = 1; m < 32; m <<= 1) {        // closed within 32-lane halves
            #pragma unroll
            for (int jj = 0; jj < 4; ++jj) {
                float ov = __shfl_xor(dmax[jj], m); int oi = __shfl_xor(didx[jj], m);
                if (ov > dmax[jj] || (ov == dmax[jj] && oi < didx[jj])) { dmax[jj] = ov; didx[jj] = oi; }
                ov = __shfl_xor(smax[jj], m); oi = __shfl_xor(sidx[jj], m);
                if (ov > smax[jj] || (ov == smax[jj] && oi < sidx[jj])) { smax[jj] = ov; sidx[jj] = oi; }
                S[jj] += __shfl_xor(S[jj], m);
                T[jj] += __shfl_xor(T[jj], m);
            }
        }
        if (ty == 0) {
            #pragma unroll
            for (int jj = 0; jj < 4; ++jj) {
                const int base = (b * NCH + ch) * L_ + pofs + pl + jj;
                out[0 * STRIDE_P + base] = dmax[jj];
                out[1 * STRIDE_P + base] = __int_as_float(didx[jj]);
                out[2 * STRIDE_P + base] = smax[jj];
                out[3 * STRIDE_P + base] = __int_as_float(sidx[jj]);
                out[4 * STRIDE_P + base] = S[jj];
                out[5 * STRIDE_P + base] = T[jj];
            }
        }
    }
    if (ch == 0 && psl == 0 && b == 0 && tid == 0) out[LOSS_IDX] = 0.f;
}

// ---------------- Kernel 2: combine chunks + mask + select + KL --------------
// grid (B), block 256 (one thread per position).
__global__ __launch_bounds__(256) void k2_combine(
    const float* __restrict__ noise, float* __restrict__ out)
{
    const int p = threadIdx.x, b = blockIdx.x;
    float dmax = -INFINITY, smax = -INFINITY, S = 0.f, T = 0.f;
    int didx = 0, sidx = 0;
    for (int ch = 0; ch < NCH; ++ch) {          // ascending chunk = ascending code idx
        const int base = (b * NCH + ch) * L_ + p;
        float dm = out[0 * STRIDE_P + base];
        int   di = __float_as_int(out[1 * STRIDE_P + base]);
        float sm = out[2 * STRIDE_P + base];
        int   si = __float_as_int(out[3 * STRIDE_P + base]);
        S += out[4 * STRIDE_P + base];
        T += out[5 * STRIDE_P + base];
        if (dm > dmax) { dmax = dm; didx = di; }
        if (sm > smax) { smax = sm; sidx = si; }
    }

    // mask: rank of noise within row (stable argsort semantics)
    __shared__ float nz[256];
    nz[p] = noise[b * L_ + p];
    __syncthreads();
    const float myv = nz[p];
    int rank = 0;
    for (int j = 0; j < 256; ++j) {
        float v = nz[j];
        rank += (v < myv) || (v == myv && j < p);
    }
    const int sel = (rank >= 128) ? sidx : didx;   // mask=1 -> stochastic branch
    out[IND_BASE + b * L_ + p] = (float)sel;

    // KL to uniform: sum_n qy*log(qy*NE) = T/S - log S + log NE   (m=0 basis)
    float kl = T / S - logf(S) + logf((float)NE_);
    __shared__ float red[256];
    red[p] = kl;
    __syncthreads();
    for (int s = 128; s > 0; s >>= 1) {
        if (p < s) red[p] += red[p + s];
        __syncthreads();
    }
    if (p == 0) atomicAdd(&out[LOSS_IDX], (KLW / 4096.f) * red[0]);
}

// ---------------- Kernel 3: z_q gather from codebook -------------------------
// grid (32, B), block 256: thread = one p, 8 d's. float4 codebook gathers
// (L2/L3-hot, 8 MiB), fully coalesced stores.
__global__ __launch_bounds__(256) void k3_gather(
    const float* __restrict__ emb, float* __restrict__ out)
{
    const int p = threadIdx.x;
    const int dc = blockIdx.x, b = blockIdx.y;
    const int sel = (int)out[IND_BASE + b * L_ + p];
    const float* er = emb + (size_t)sel * ED_ + dc * 8;
    const float4 e0 = *(const float4*)(er);
    const float4 e1 = *(const float4*)(er + 4);
    const size_t ob = ((size_t)b * ED_ + dc * 8) * L_ + p;
    out[ob + 0 * L_] = e0.x; out[ob + 1 * L_] = e0.y;
    out[ob + 2 * L_] = e0.z; out[ob + 3 * L_] = e0.w;
    out[ob + 4 * L_] = e1.x; out[ob + 5 * L_] = e1.y;
    out[ob + 6 * L_] = e1.z; out[ob + 7 * L_] = e1.w;
}

extern "C" void kernel_launch(void* const* d_in, const int* in_sizes, int n_in,
                              void* d_out, int out_size, void* d_ws, size_t ws_size,
                              hipStream_t stream) {
    const float* z     = (const float*)d_in[0];
    const float* pw    = (const float*)d_in[1];
    const float* pb    = (const float*)d_in[2];
    const float* emb   = (const float*)d_in[3];
    const float* gum   = (const float*)d_in[4];
    const float* noise = (const float*)d_in[5];
    float* out = (float*)d_out;

    hipLaunchKernelGGL(k1_gemm, dim3(NCH, 2, B_), dim3(512), 0, stream, z, pw, pb, gum, out);
    hipLaunchKernelGGL(k2_combine, dim3(B_), dim3(256), 0, stream, noise, out);
    hipLaunchKernelGGL(k3_gather, dim3(32, B_), dim3(256), 0, stream, emb, out);
}

// Round 8
// 421.875 us; speedup vs baseline: 2.1045x; 1.0445x over previous
//
#include <hip/hip_runtime.h>
#include <math.h>

#define B_ 16
#define NH_ 256                // K (channels)
#define NE_ 8192               // codebook size
#define ED_ 256
#define L_ 256                 // positions per sample
#define NCH 32                 // n-chunks
#define CHUNK 256              // codes per chunk
#define STRIDE_P (B_ * NCH * L_)   // 131072 per field; 6 fields < 1048576 (z_q region)
#define LOSS_IDX 1048576
#define IND_BASE 1048577
#define KLW 0.0005f
#define RS 24                  // LDS row stride in halves (48B rows: 16 valid + pad)

typedef _Float16 f16x8 __attribute__((ext_vector_type(8)));
typedef float f32x16 __attribute__((ext_vector_type(16)));

// ---------------- Kernel 1: fp16-split 3-pass MFMA GEMM + fused epilogue -----
// grid (NCH, B), block 512 = 8 waves. Per wg: 256n x 256p, K=256 in 16 steps.
// Wave w: n-tiles (w&1)*4..+3, p-tiles (w>>1)*2..+1 (32x32 tiles, 16 acc each).
// fp32 -> (hi,lo) fp16 split at staging; logits = hh + hl + lh (ll ~ 2^-22, dropped).
__global__ __launch_bounds__(512, 2) void k1_mfma(
    const float* __restrict__ z, const float* __restrict__ pw,
    const float* __restrict__ pb, const float* __restrict__ gum,
    float* __restrict__ out)
{
    __shared__ __align__(16) _Float16 Wh[256 * RS];
    __shared__ __align__(16) _Float16 Wl[256 * RS];
    __shared__ __align__(16) _Float16 Zh[256 * RS];
    __shared__ __align__(16) _Float16 Zl[256 * RS];

    const int tid = threadIdx.x;
    const int ch = blockIdx.x, b = blockIdx.y;
    const int nc0 = ch * CHUNK;
    const int w = tid >> 6;            // wave 0..7
    const int lane = tid & 63;
    const int col = lane & 31;
    const int khl = lane >> 5;         // k-half for fragments
    const int wn = w & 1;              // n-half (4 n-tiles)
    const int wp = w >> 1;             // p-quarter (2 p-tiles)

    // staging map: thread -> (row 0..255, k-half 0..1); 8 k-consecutive fp32 each
    const int sn = tid >> 1;
    const int sh = tid & 1;
    const float* wsrc = pw + (size_t)(nc0 + sn) * NH_ + sh * 8;        // +kt*16
    const float* zsrc = z + ((size_t)b * NH_ + sh * 8) * L_ + sn;      // +(kt*16+j)*L_

    f32x16 acc[4][2];
    {
        f32x16 zz = {};
        #pragma unroll
        for (int i = 0; i < 4; ++i)
            #pragma unroll
            for (int j = 0; j < 2; ++j) acc[i][j] = zz;
    }

    // prefetch kt=0
    float4 wv0 = *(const float4*)(wsrc);
    float4 wv1 = *(const float4*)(wsrc + 4);
    float zr[8];
    #pragma unroll
    for (int j = 0; j < 8; ++j) zr[j] = zsrc[(size_t)j * L_];

    for (int kt = 0; kt < 16; ++kt) {
        __syncthreads();               // previous step's frag reads complete
        {   // split + stage (one b128 write per plane)
            float wv[8] = {wv0.x, wv0.y, wv0.z, wv0.w, wv1.x, wv1.y, wv1.z, wv1.w};
            f16x8 h8, l8;
            #pragma unroll
            for (int j = 0; j < 8; ++j) {
                _Float16 h = (_Float16)wv[j];
                h8[j] = h;
                l8[j] = (_Float16)(wv[j] - (float)h);
            }
            *(f16x8*)&Wh[sn * RS + sh * 8] = h8;
            *(f16x8*)&Wl[sn * RS + sh * 8] = l8;
            #pragma unroll
            for (int j = 0; j < 8; ++j) {
                _Float16 h = (_Float16)zr[j];
                h8[j] = h;
                l8[j] = (_Float16)(zr[j] - (float)h);
            }
            *(f16x8*)&Zh[sn * RS + sh * 8] = h8;
            *(f16x8*)&Zl[sn * RS + sh * 8] = l8;
        }
        if (kt < 15) {                 // T14: issue next-tile loads before compute
            wv0 = *(const float4*)(wsrc + (kt + 1) * 16);
            wv1 = *(const float4*)(wsrc + (kt + 1) * 16 + 4);
            #pragma unroll
            for (int j = 0; j < 8; ++j)
                zr[j] = zsrc[((size_t)(kt + 1) * 16 + j) * L_];
        }
        __syncthreads();

        f16x8 bh[2], bl[2];
        #pragma unroll
        for (int pt = 0; pt < 2; ++pt) {
            const int pr = (wp * 2 + pt) * 32 + col;
            bh[pt] = *(const f16x8*)&Zh[pr * RS + khl * 8];
            bl[pt] = *(const f16x8*)&Zl[pr * RS + khl * 8];
        }
        #pragma unroll
        for (int nt = 0; nt < 4; ++nt) {
            const int nr = (wn * 4 + nt) * 32 + col;
            f16x8 ah = *(const f16x8*)&Wh[nr * RS + khl * 8];
            f16x8 al = *(const f16x8*)&Wl[nr * RS + khl * 8];
            #pragma unroll
            for (int pt = 0; pt < 2; ++pt) {
                acc[nt][pt] = __builtin_amdgcn_mfma_f32_32x32x16_f16(ah, bh[pt], acc[nt][pt], 0, 0, 0);
                acc[nt][pt] = __builtin_amdgcn_mfma_f32_32x32x16_f16(ah, bl[pt], acc[nt][pt], 0, 0, 0);
                acc[nt][pt] = __builtin_amdgcn_mfma_f32_32x32x16_f16(al, bh[pt], acc[nt][pt], 0, 0, 0);
            }
        }
    }
    __syncthreads();                   // all frag reads done; LDS reusable

    // ---- epilogue: bias + gumbel + argmaxes + exp sums -----------------------
    float dmax[2] = {-INFINITY, -INFINITY}, smax[2] = {-INFINITY, -INFINITY};
    float S[2] = {0.f, 0.f}, T[2] = {0.f, 0.f};
    int didx[2] = {0x7fffffff, 0x7fffffff}, sidx[2] = {0x7fffffff, 0x7fffffff};
    const float* gb = gum + ((size_t)b * NE_ + nc0) * L_;
    const int p0 = (wp * 2) * 32 + col;
    const int p1 = p0 + 32;
    #pragma unroll
    for (int nt = 0; nt < 4; ++nt) {
        #pragma unroll
        for (int r = 0; r < 16; ++r) {
            // C/D layout: col = lane&31, row = (r&3) + 8*(r>>2) + 4*(lane>>5)
            const int nl = (wn * 4 + nt) * 32 + (r & 3) + 8 * (r >> 2) + 4 * khl;
            const int ng = nc0 + nl;
            const float pbv = pb[ng];
            const float l0 = acc[nt][0][r] + pbv;
            const float l1 = acc[nt][1][r] + pbv;
            if (l0 > dmax[0]) { dmax[0] = l0; didx[0] = ng; }   // nl ascending in-lane
            if (l1 > dmax[1]) { dmax[1] = l1; didx[1] = ng; }
            const float s0 = l0 + gb[(size_t)nl * L_ + p0];
            const float s1 = l1 + gb[(size_t)nl * L_ + p1];
            if (s0 > smax[0]) { smax[0] = s0; sidx[0] = ng; }
            if (s1 > smax[1]) { smax[1] = s1; sidx[1] = ng; }
            const float e0 = __expf(l0), e1 = __expf(l1);
            S[0] += e0; S[1] += e1;
            T[0] = fmaf(l0, e0, T[0]);
            T[1] = fmaf(l1, e1, T[1]);
        }
    }
    // lane ^ 32 combine (row-half): tie -> lower code index
    #pragma unroll
    for (int pt = 0; pt < 2; ++pt) {
        float ov; int oi;
        ov = __shfl_xor(dmax[pt], 32); oi = __shfl_xor(didx[pt], 32);
        if (ov > dmax[pt] || (ov == dmax[pt] && oi < didx[pt])) { dmax[pt] = ov; didx[pt] = oi; }
        ov = __shfl_xor(smax[pt], 32); oi = __shfl_xor(sidx[pt], 32);
        if (ov > smax[pt] || (ov == smax[pt] && oi < sidx[pt])) { smax[pt] = ov; sidx[pt] = oi; }
        S[pt] += __shfl_xor(S[pt], 32);
        T[pt] += __shfl_xor(T[pt], 32);
    }
    // wave-pair (n-half) combine via LDS: layout [w][pt][field][32]
    float* ep = (float*)Wh;
    if (lane < 32) {
        #pragma unroll
        for (int pt = 0; pt < 2; ++pt) {
            const int base = ((w * 2 + pt) * 6) * 32 + lane;
            ep[base + 0 * 32] = dmax[pt];
            ep[base + 1 * 32] = __int_as_float(didx[pt]);
            ep[base + 2 * 32] = smax[pt];
            ep[base + 3 * 32] = __int_as_float(sidx[pt]);
            ep[base + 4 * 32] = S[pt];
            ep[base + 5 * 32] = T[pt];
        }
    }
    __syncthreads();
    if (wn == 0 && lane < 32) {
        #pragma unroll
        for (int pt = 0; pt < 2; ++pt) {
            const int pbase = (((w + 1) * 2 + pt) * 6) * 32 + lane;
            float ov = ep[pbase + 0 * 32]; int oi = __float_as_int(ep[pbase + 1 * 32]);
            if (ov > dmax[pt] || (ov == dmax[pt] && oi < didx[pt])) { dmax[pt] = ov; didx[pt] = oi; }
            ov = ep[pbase + 2 * 32]; oi = __float_as_int(ep[pbase + 3 * 32]);
            if (ov > smax[pt] || (ov == smax[pt] && oi < sidx[pt])) { smax[pt] = ov; sidx[pt] = oi; }
            S[pt] += ep[pbase + 4 * 32];
            T[pt] += ep[pbase + 5 * 32];
            const int p = (wp * 2 + pt) * 32 + lane;
            const int gbase2 = (b * NCH + ch) * L_ + p;
            out[0 * STRIDE_P + gbase2] = dmax[pt];
            out[1 * STRIDE_P + gbase2] = __int_as_float(didx[pt]);
            out[2 * STRIDE_P + gbase2] = smax[pt];
            out[3 * STRIDE_P + gbase2] = __int_as_float(sidx[pt]);
            out[4 * STRIDE_P + gbase2] = S[pt];
            out[5 * STRIDE_P + gbase2] = T[pt];
        }
    }
    if (ch == 0 && b == 0 && tid == 0) out[LOSS_IDX] = 0.f;   // zero for k2 atomics
}

// ---------------- Kernel 2: combine chunks + mask + select + KL --------------
// grid (B, 8), block 256 = 32 p x 8 chunk-groups.
__global__ __launch_bounds__(256) void k2_combine(
    const float* __restrict__ noise, float* __restrict__ out)
{
    const int b = blockIdx.x, pg = blockIdx.y;
    const int t = threadIdx.x;
    const int pl = t & 31, cg = t >> 5;
    const int p = pg * 32 + pl;
    float dmax = -INFINITY, smax = -INFINITY, S = 0.f, T = 0.f;
    int didx = 0x7fffffff, sidx = 0x7fffffff;
    #pragma unroll
    for (int i = 0; i < 4; ++i) {
        const int ch = cg * 4 + i;
        const int base = (b * NCH + ch) * L_ + p;
        float dm = out[0 * STRIDE_P + base]; int di = __float_as_int(out[1 * STRIDE_P + base]);
        float sm = out[2 * STRIDE_P + base]; int si = __float_as_int(out[3 * STRIDE_P + base]);
        S += out[4 * STRIDE_P + base];
        T += out[5 * STRIDE_P + base];
        if (dm > dmax || (dm == dmax && di < didx)) { dmax = dm; didx = di; }
        if (sm > smax || (sm == smax && si < sidx)) { smax = sm; sidx = si; }
    }
    __shared__ float red[6][8][32];
    red[0][cg][pl] = dmax; red[1][cg][pl] = __int_as_float(didx);
    red[2][cg][pl] = smax; red[3][cg][pl] = __int_as_float(sidx);
    red[4][cg][pl] = S;    red[5][cg][pl] = T;
    for (int s = 4; s > 0; s >>= 1) {
        __syncthreads();
        if (cg < s) {
            float dm = red[0][cg + s][pl]; int di = __float_as_int(red[1][cg + s][pl]);
            float sm = red[2][cg + s][pl]; int si = __float_as_int(red[3][cg + s][pl]);
            if (dm > dmax || (dm == dmax && di < didx)) { dmax = dm; didx = di; }
            if (sm > smax || (sm == smax && si < sidx)) { smax = sm; sidx = si; }
            S += red[4][cg + s][pl]; T += red[5][cg + s][pl];
            red[0][cg][pl] = dmax; red[1][cg][pl] = __int_as_float(didx);
            red[2][cg][pl] = smax; red[3][cg][pl] = __int_as_float(sidx);
            red[4][cg][pl] = S;    red[5][cg][pl] = T;
        }
    }
    // rank of noise within row (stable argsort semantics)
    __shared__ float nz[256];
    nz[t] = noise[b * L_ + t];
    __syncthreads();
    const float myv = nz[p];
    int cnt = 0;
    #pragma unroll
    for (int jj = 0; jj < 32; ++jj) {
        const int j = cg * 32 + jj;
        const float v = nz[j];
        cnt += (v < myv) || (v == myv && j < p);
    }
    __shared__ int rc[8][32];
    rc[cg][pl] = cnt;
    for (int s = 4; s > 0; s >>= 1) {
        __syncthreads();
        if (cg < s) rc[cg][pl] += rc[cg + s][pl];
    }
    __syncthreads();
    if (cg == 0) {                     // threads 0..31 = lanes 0..31 of wave 0
        const int rank = rc[0][pl];
        const int sel = (rank >= 128) ? sidx : didx;   // mask=1 -> stochastic
        out[IND_BASE + b * L_ + p] = (float)sel;
        float kl = T / S - logf(S) + logf((float)NE_);
        #pragma unroll
        for (int m = 1; m < 32; m <<= 1) kl += __shfl_xor(kl, m);
        if (pl == 0) atomicAdd(&out[LOSS_IDX], (KLW / 4096.f) * kl);
    }
}

// ---------------- Kernel 3: z_q gather from codebook -------------------------
__global__ __launch_bounds__(256) void k3_gather(
    const float* __restrict__ emb, float* __restrict__ out)
{
    const int p = threadIdx.x;
    const int dc = blockIdx.x, b = blockIdx.y;
    const int sel = (int)out[IND_BASE + b * L_ + p];
    const float* er = emb + (size_t)sel * ED_ + dc * 8;
    const float4 e0 = *(const float4*)(er);
    const float4 e1 = *(const float4*)(er + 4);
    const size_t ob = ((size_t)b * ED_ + dc * 8) * L_ + p;
    out[ob + 0 * L_] = e0.x; out[ob + 1 * L_] = e0.y;
    out[ob + 2 * L_] = e0.z; out[ob + 3 * L_] = e0.w;
    out[ob + 4 * L_] = e1.x; out[ob + 5 * L_] = e1.y;
    out[ob + 6 * L_] = e1.z; out[ob + 7 * L_] = e1.w;
}

extern "C" void kernel_launch(void* const* d_in, const int* in_sizes, int n_in,
                              void* d_out, int out_size, void* d_ws, size_t ws_size,
                              hipStream_t stream) {
    const float* z     = (const float*)d_in[0];
    const float* pw    = (const float*)d_in[1];
    const float* pb    = (const float*)d_in[2];
    const float* emb   = (const float*)d_in[3];
    const float* gum   = (const float*)d_in[4];
    const float* noise = (const float*)d_in[5];
    float* out = (float*)d_out;

    hipLaunchKernelGGL(k1_mfma, dim3(NCH, B_), dim3(512), 0, stream, z, pw, pb, gum, out);
    hipLaunchKernelGGL(k2_combine, dim3(B_, 8), dim3(256), 0, stream, noise, out);
    hipLaunchKernelGGL(k3_gather, dim3(32, B_), dim3(256), 0, stream, emb, out);
}

// Round 12
// 412.607 us; speedup vs baseline: 2.1518x; 1.0225x over previous
//
#include <hip/hip_runtime.h>
#include <math.h>

#define B_ 16
#define NH_ 256                // K (channels)
#define NE_ 8192               // codebook size
#define ED_ 256
#define L_ 256                 // positions per sample
#define NCH 32                 // n-chunks
#define CHUNK 256              // codes per chunk
#define STRIDE_P (B_ * NCH * L_)   // 131072 per field; 6 fields < 1048576 (z_q region)
#define LOSS_IDX 1048576
#define IND_BASE 1048577
#define KLW 0.0005f
#define RS 24                  // LDS row stride in halves (48B rows: 16 valid + pad)

typedef _Float16 f16x8 __attribute__((ext_vector_type(8)));
typedef float f32x16 __attribute__((ext_vector_type(16)));

// ---------------- Kernel 1: fp16-split 3-pass MFMA GEMM + fused epilogue -----
// grid (NCH, B), block 512 = 8 waves. Per wg: 256n x 256p, K=256 in 16 steps.
// Wave w: n-tiles (w&1)*4..+3, p-tiles (w>>1)*2..+1 (32x32 tiles, 16 acc each).
// fp32 -> (hi,lo) fp16 split at staging; logits = hh + hl + lh (ll ~ 2^-22, dropped).
// waves_per_eu(2,2): budget 512/2 = 256 regs/wave. Round-8 failure: launch_bounds
// (512,2) produced a 128-reg cap -> acc[4][2] (128 f32) spilled, 162 MB scratch
// writes, MfmaUtil 8%. One 8-wave block/CU is the occupancy we measured anyway.
__global__ __launch_bounds__(512)
__attribute__((amdgpu_waves_per_eu(2, 2)))
void k1_mfma(
    const float* __restrict__ z, const float* __restrict__ pw,
    const float* __restrict__ pb, const float* __restrict__ gum,
    float* __restrict__ out)
{
    __shared__ __align__(16) _Float16 Wh[256 * RS];
    __shared__ __align__(16) _Float16 Wl[256 * RS];
    __shared__ __align__(16) _Float16 Zh[256 * RS];
    __shared__ __align__(16) _Float16 Zl[256 * RS];

    const int tid = threadIdx.x;
    const int ch = blockIdx.x, b = blockIdx.y;
    const int nc0 = ch * CHUNK;
    const int w = tid >> 6;            // wave 0..7
    const int lane = tid & 63;
    const int col = lane & 31;
    const int khl = lane >> 5;         // k-half for fragments
    const int wn = w & 1;              // n-half (4 n-tiles)
    const int wp = w >> 1;             // p-quarter (2 p-tiles)

    // staging map: thread -> (row 0..255, k-half 0..1); 8 k-consecutive fp32 each
    const int sn = tid >> 1;
    const int sh = tid & 1;
    const float* wsrc = pw + (size_t)(nc0 + sn) * NH_ + sh * 8;        // +kt*16
    const float* zsrc = z + ((size_t)b * NH_ + sh * 8) * L_ + sn;      // +(kt*16+j)*L_

    f32x16 acc[4][2];
    {
        f32x16 zz = {};
        #pragma unroll
        for (int i = 0; i < 4; ++i)
            #pragma unroll
            for (int j = 0; j < 2; ++j) acc[i][j] = zz;
    }

    // prefetch kt=0
    float4 wv0 = *(const float4*)(wsrc);
    float4 wv1 = *(const float4*)(wsrc + 4);
    float zr[8];
    #pragma unroll
    for (int j = 0; j < 8; ++j) zr[j] = zsrc[(size_t)j * L_];

    for (int kt = 0; kt < 16; ++kt) {
        __syncthreads();               // previous step's frag reads complete
        {   // split + stage (one b128 write per plane)
            float wv[8] = {wv0.x, wv0.y, wv0.z, wv0.w, wv1.x, wv1.y, wv1.z, wv1.w};
            f16x8 h8, l8;
            #pragma unroll
            for (int j = 0; j < 8; ++j) {
                _Float16 h = (_Float16)wv[j];
                h8[j] = h;
                l8[j] = (_Float16)(wv[j] - (float)h);
            }
            *(f16x8*)&Wh[sn * RS + sh * 8] = h8;
            *(f16x8*)&Wl[sn * RS + sh * 8] = l8;
            #pragma unroll
            for (int j = 0; j < 8; ++j) {
                _Float16 h = (_Float16)zr[j];
                h8[j] = h;
                l8[j] = (_Float16)(zr[j] - (float)h);
            }
            *(f16x8*)&Zh[sn * RS + sh * 8] = h8;
            *(f16x8*)&Zl[sn * RS + sh * 8] = l8;
        }
        if (kt < 15) {                 // T14: issue next-tile loads before compute
            wv0 = *(const float4*)(wsrc + (kt + 1) * 16);
            wv1 = *(const float4*)(wsrc + (kt + 1) * 16 + 4);
            #pragma unroll
            for (int j = 0; j < 8; ++j)
                zr[j] = zsrc[((size_t)(kt + 1) * 16 + j) * L_];
        }
        __syncthreads();

        f16x8 bh[2], bl[2];
        #pragma unroll
        for (int pt = 0; pt < 2; ++pt) {
            const int pr = (wp * 2 + pt) * 32 + col;
            bh[pt] = *(const f16x8*)&Zh[pr * RS + khl * 8];
            bl[pt] = *(const f16x8*)&Zl[pr * RS + khl * 8];
        }
        #pragma unroll
        for (int nt = 0; nt < 4; ++nt) {
            const int nr = (wn * 4 + nt) * 32 + col;
            f16x8 ah = *(const f16x8*)&Wh[nr * RS + khl * 8];
            f16x8 al = *(const f16x8*)&Wl[nr * RS + khl * 8];
            #pragma unroll
            for (int pt = 0; pt < 2; ++pt) {
                acc[nt][pt] = __builtin_amdgcn_mfma_f32_32x32x16_f16(ah, bh[pt], acc[nt][pt], 0, 0, 0);
                acc[nt][pt] = __builtin_amdgcn_mfma_f32_32x32x16_f16(ah, bl[pt], acc[nt][pt], 0, 0, 0);
                acc[nt][pt] = __builtin_amdgcn_mfma_f32_32x32x16_f16(al, bh[pt], acc[nt][pt], 0, 0, 0);
            }
        }
    }
    __syncthreads();                   // all frag reads done; LDS reusable

    // ---- epilogue: bias + gumbel + argmaxes + exp sums -----------------------
    float dmax[2] = {-INFINITY, -INFINITY}, smax[2] = {-INFINITY, -INFINITY};
    float S[2] = {0.f, 0.f}, T[2] = {0.f, 0.f};
    int didx[2] = {0x7fffffff, 0x7fffffff}, sidx[2] = {0x7fffffff, 0x7fffffff};
    const float* gb = gum + ((size_t)b * NE_ + nc0) * L_;
    const int p0 = (wp * 2) * 32 + col;
    const int p1 = p0 + 32;
    #pragma unroll
    for (int nt = 0; nt < 4; ++nt) {
        #pragma unroll
        for (int r = 0; r < 16; ++r) {
            // C/D layout: col = lane&31, row = (r&3) + 8*(r>>2) + 4*(lane>>5)
            const int nl = (wn * 4 + nt) * 32 + (r & 3) + 8 * (r >> 2) + 4 * khl;
            const int ng = nc0 + nl;
            const float pbv = pb[ng];
            const float l0 = acc[nt][0][r] + pbv;
            const float l1 = acc[nt][1][r] + pbv;
            if (l0 > dmax[0]) { dmax[0] = l0; didx[0] = ng; }   // nl ascending in-lane
            if (l1 > dmax[1]) { dmax[1] = l1; didx[1] = ng; }
            const float s0 = l0 + gb[(size_t)nl * L_ + p0];
            const float s1 = l1 + gb[(size_t)nl * L_ + p1];
            if (s0 > smax[0]) { smax[0] = s0; sidx[0] = ng; }
            if (s1 > smax[1]) { smax[1] = s1; sidx[1] = ng; }
            const float e0 = __expf(l0), e1 = __expf(l1);
            S[0] += e0; S[1] += e1;
            T[0] = fmaf(l0, e0, T[0]);
            T[1] = fmaf(l1, e1, T[1]);
        }
    }
    // lane ^ 32 combine (row-half): tie -> lower code index
    #pragma unroll
    for (int pt = 0; pt < 2; ++pt) {
        float ov; int oi;
        ov = __shfl_xor(dmax[pt], 32); oi = __shfl_xor(didx[pt], 32);
        if (ov > dmax[pt] || (ov == dmax[pt] && oi < didx[pt])) { dmax[pt] = ov; didx[pt] = oi; }
        ov = __shfl_xor(smax[pt], 32); oi = __shfl_xor(sidx[pt], 32);
        if (ov > smax[pt] || (ov == smax[pt] && oi < sidx[pt])) { smax[pt] = ov; sidx[pt] = oi; }
        S[pt] += __shfl_xor(S[pt], 32);
        T[pt] += __shfl_xor(T[pt], 32);
    }
    // wave-pair (n-half) combine via LDS: layout [w][pt][field][32]
    float* ep = (float*)Wh;
    if (lane < 32) {
        #pragma unroll
        for (int pt = 0; pt < 2; ++pt) {
            const int base = ((w * 2 + pt) * 6) * 32 + lane;
            ep[base + 0 * 32] = dmax[pt];
            ep[base + 1 * 32] = __int_as_float(didx[pt]);
            ep[base + 2 * 32] = smax[pt];
            ep[base + 3 * 32] = __int_as_float(sidx[pt]);
            ep[base + 4 * 32] = S[pt];
            ep[base + 5 * 32] = T[pt];
        }
    }
    __syncthreads();
    if (wn == 0 && lane < 32) {
        #pragma unroll
        for (int pt = 0; pt < 2; ++pt) {
            const int pbase = (((w + 1) * 2 + pt) * 6) * 32 + lane;
            float ov = ep[pbase + 0 * 32]; int oi = __float_as_int(ep[pbase + 1 * 32]);
            if (ov > dmax[pt] || (ov == dmax[pt] && oi < didx[pt])) { dmax[pt] = ov; didx[pt] = oi; }
            ov = ep[pbase + 2 * 32]; oi = __float_as_int(ep[pbase + 3 * 32]);
            if (ov > smax[pt] || (ov == smax[pt] && oi < sidx[pt])) { smax[pt] = ov; sidx[pt] = oi; }
            S[pt] += ep[pbase + 4 * 32];
            T[pt] += ep[pbase + 5 * 32];
            const int p = (wp * 2 + pt) * 32 + lane;
            const int gbase2 = (b * NCH + ch) * L_ + p;
            out[0 * STRIDE_P + gbase2] = dmax[pt];
            out[1 * STRIDE_P + gbase2] = __int_as_float(didx[pt]);
            out[2 * STRIDE_P + gbase2] = smax[pt];
            out[3 * STRIDE_P + gbase2] = __int_as_float(sidx[pt]);
            out[4 * STRIDE_P + gbase2] = S[pt];
            out[5 * STRIDE_P + gbase2] = T[pt];
        }
    }
    if (ch == 0 && b == 0 && tid == 0) out[LOSS_IDX] = 0.f;   // zero for k2 atomics
}

// ---------------- Kernel 2: combine chunks + mask + select + KL --------------
// grid (B, 8), block 256 = 32 p x 8 chunk-groups.
__global__ __launch_bounds__(256) void k2_combine(
    const float* __restrict__ noise, float* __restrict__ out)
{
    const int b = blockIdx.x, pg = blockIdx.y;
    const int t = threadIdx.x;
    const int pl = t & 31, cg = t >> 5;
    const int p = pg * 32 + pl;
    float dmax = -INFINITY, smax = -INFINITY, S = 0.f, T = 0.f;
    int didx = 0x7fffffff, sidx = 0x7fffffff;
    #pragma unroll
    for (int i = 0; i < 4; ++i) {
        const int ch = cg * 4 + i;
        const int base = (b * NCH + ch) * L_ + p;
        float dm = out[0 * STRIDE_P + base]; int di = __float_as_int(out[1 * STRIDE_P + base]);
        float sm = out[2 * STRIDE_P + base]; int si = __float_as_int(out[3 * STRIDE_P + base]);
        S += out[4 * STRIDE_P + base];
        T += out[5 * STRIDE_P + base];
        if (dm > dmax || (dm == dmax && di < didx)) { dmax = dm; didx = di; }
        if (sm > smax || (sm == smax && si < sidx)) { smax = sm; sidx = si; }
    }
    __shared__ float red[6][8][32];
    red[0][cg][pl] = dmax; red[1][cg][pl] = __int_as_float(didx);
    red[2][cg][pl] = smax; red[3][cg][pl] = __int_as_float(sidx);
    red[4][cg][pl] = S;    red[5][cg][pl] = T;
    for (int s = 4; s > 0; s >>= 1) {
        __syncthreads();
        if (cg < s) {
            float dm = red[0][cg + s][pl]; int di = __float_as_int(red[1][cg + s][pl]);
            float sm = red[2][cg + s][pl]; int si = __float_as_int(red[3][cg + s][pl]);
            if (dm > dmax || (dm == dmax && di < didx)) { dmax = dm; didx = di; }
            if (sm > smax || (sm == smax && si < sidx)) { smax = sm; sidx = si; }
            S += red[4][cg + s][pl]; T += red[5][cg + s][pl];
            red[0][cg][pl] = dmax; red[1][cg][pl] = __int_as_float(didx);
            red[2][cg][pl] = smax; red[3][cg][pl] = __int_as_float(sidx);
            red[4][cg][pl] = S;    red[5][cg][pl] = T;
        }
    }
    // rank of noise within row (stable argsort semantics)
    __shared__ float nz[256];
    nz[t] = noise[b * L_ + t];
    __syncthreads();
    const float myv = nz[p];
    int cnt = 0;
    #pragma unroll
    for (int jj = 0; jj < 32; ++jj) {
        const int j = cg * 32 + jj;
        const float v = nz[j];
        cnt += (v < myv) || (v == myv && j < p);
    }
    __shared__ int rc[8][32];
    rc[cg][pl] = cnt;
    for (int s = 4; s > 0; s >>= 1) {
        __syncthreads();
        if (cg < s) rc[cg][pl] += rc[cg + s][pl];
    }
    __syncthreads();
    if (cg == 0) {                     // threads 0..31 = lanes 0..31 of wave 0
        const int rank = rc[0][pl];
        const int sel = (rank >= 128) ? sidx : didx;   // mask=1 -> stochastic
        out[IND_BASE + b * L_ + p] = (float)sel;
        float kl = T / S - logf(S) + logf((float)NE_);
        #pragma unroll
        for (int m = 1; m < 32; m <<= 1) kl += __shfl_xor(kl, m);
        if (pl == 0) atomicAdd(&out[LOSS_IDX], (KLW / 4096.f) * kl);
    }
}

// ---------------- Kernel 3: z_q gather from codebook -------------------------
__global__ __launch_bounds__(256) void k3_gather(
    const float* __restrict__ emb, float* __restrict__ out)
{
    const int p = threadIdx.x;
    const int dc = blockIdx.x, b = blockIdx.y;
    const int sel = (int)out[IND_BASE + b * L_ + p];
    const float* er = emb + (size_t)sel * ED_ + dc * 8;
    const float4 e0 = *(const float4*)(er);
    const float4 e1 = *(const float4*)(er + 4);
    const size_t ob = ((size_t)b * ED_ + dc * 8) * L_ + p;
    out[ob + 0 * L_] = e0.x; out[ob + 1 * L_] = e0.y;
    out[ob + 2 * L_] = e0.z; out[ob + 3 * L_] = e0.w;
    out[ob + 4 * L_] = e1.x; out[ob + 5 * L_] = e1.y;
    out[ob + 6 * L_] = e1.z; out[ob + 7 * L_] = e1.w;
}

extern "C" void kernel_launch(void* const* d_in, const int* in_sizes, int n_in,
                              void* d_out, int out_size, void* d_ws, size_t ws_size,
                              hipStream_t stream) {
    const float* z     = (const float*)d_in[0];
    const float* pw    = (const float*)d_in[1];
    const float* pb    = (const float*)d_in[2];
    const float* emb   = (const float*)d_in[3];
    const float* gum   = (const float*)d_in[4];
    const float* noise = (const float*)d_in[5];
    float* out = (float*)d_out;

    hipLaunchKernelGGL(k1_mfma, dim3(NCH, B_), dim3(512), 0, stream, z, pw, pb, gum, out);
    hipLaunchKernelGGL(k2_combine, dim3(B_, 8), dim3(256), 0, stream, noise, out);
    hipLaunchKernelGGL(k3_gather, dim3(32, B_), dim3(256), 0, stream, emb, out);
}

// Round 14
// 293.362 us; speedup vs baseline: 3.0265x; 1.4065x over previous
//
#include <hip/hip_runtime.h>
#include <math.h>

#define B_ 16
#define NH_ 256                // K (channels)
#define NE_ 8192               // codebook size
#define ED_ 256
#define L_ 256                 // positions per sample
#define NCH 32                 // n-chunks
#define CHUNK 256              // codes per chunk
#define STRIDE_P (B_ * NCH * L_)   // 131072 per field; 6 fields < 1048576 (z_q region)
#define LOSS_IDX 1048576
#define IND_BASE 1048577
#define KLW 0.0005f
#define RS 24                  // LDS row stride in halves (48B rows: 16 valid + pad)

typedef _Float16 f16x8 __attribute__((ext_vector_type(8)));
typedef _Float16 f16x4 __attribute__((ext_vector_type(4)));
typedef float f32x16 __attribute__((ext_vector_type(16)));

// ---------------- Kernel 1: fp16-split 3-pass MFMA GEMM + fused epilogue -----
// grid (NCH, 2, B), block 512 = 8 waves. Per wg: 256n x 128p, K=256 in 16 steps.
// Wave w: wn=w&3 (n-pair), wp=w>>2 (p-pair); 2x2 tiles of 32x32 -> acc[2][2]
// = 64 VGPRs. EMPIRICAL REG RULE (rounds 3/8/12): compiler caps threads*regs
// = 65536/block (512thr -> 128 regs) and amdgpu_waves_per_eu does NOT override;
// the only fix that works is fitting under the cap. Budget here: 64 acc + 24
// frag + 12 prefetch + ~14 addr = ~115 < 128. 2 blocks/CU (LDS 36KB).
// fp32 -> (hi,lo) fp16 split at staging; logits = hh + hl + lh (ll ~ 2^-22).
__global__ __launch_bounds__(512) void k1_mfma(
    const float* __restrict__ z, const float* __restrict__ pw,
    const float* __restrict__ pb, const float* __restrict__ gum,
    float* __restrict__ out)
{
    __shared__ __align__(16) _Float16 Wh[256 * RS];   // 12 KB
    __shared__ __align__(16) _Float16 Wl[256 * RS];
    __shared__ __align__(16) _Float16 Zh[128 * RS];   // 6 KB
    __shared__ __align__(16) _Float16 Zl[128 * RS];

    const int tid = threadIdx.x;
    const int ch = blockIdx.x, psl = blockIdx.y, b = blockIdx.z;
    const int nc0 = ch * CHUNK;
    const int pofs = psl * 128;
    const int w = tid >> 6;            // wave 0..7
    const int lane = tid & 63;
    const int col = lane & 31;
    const int khl = lane >> 5;         // k-half for fragments
    const int wn = w & 3;              // n-pair index (2 n-tiles each)
    const int wp = w >> 2;             // p-pair index (2 p-tiles each)

    // W staging: thread -> (row sn 0..255, k-half sh); 8 k-consecutive fp32
    const int sn = tid >> 1;
    const int sh = tid & 1;
    const float* wsrc = pw + (size_t)(nc0 + sn) * NH_ + sh * 8;        // +kt*16
    // Z staging: thread -> (p-row zn 0..127, k-quarter zq); 4 fp32
    const int zn = tid >> 2;
    const int zq = tid & 3;
    const float* zsrc = z + ((size_t)b * NH_ + zq * 4) * L_ + pofs + zn; // +(kt*16+j)*L_

    f32x16 acc[2][2];
    {
        f32x16 zz = {};
        #pragma unroll
        for (int i = 0; i < 2; ++i)
            #pragma unroll
            for (int j = 0; j < 2; ++j) acc[i][j] = zz;
    }

    // prefetch kt=0
    float4 wv0 = *(const float4*)(wsrc);
    float4 wv1 = *(const float4*)(wsrc + 4);
    float zr[4];
    #pragma unroll
    for (int j = 0; j < 4; ++j) zr[j] = zsrc[(size_t)j * L_];

    for (int kt = 0; kt < 16; ++kt) {
        __syncthreads();               // previous step's frag reads complete
        {   // split + stage
            float wv[8] = {wv0.x, wv0.y, wv0.z, wv0.w, wv1.x, wv1.y, wv1.z, wv1.w};
            f16x8 h8, l8;
            #pragma unroll
            for (int j = 0; j < 8; ++j) {
                _Float16 h = (_Float16)wv[j];
                h8[j] = h;
                l8[j] = (_Float16)(wv[j] - (float)h);
            }
            *(f16x8*)&Wh[sn * RS + sh * 8] = h8;
            *(f16x8*)&Wl[sn * RS + sh * 8] = l8;
            f16x4 h4, l4;
            #pragma unroll
            for (int j = 0; j < 4; ++j) {
                _Float16 h = (_Float16)zr[j];
                h4[j] = h;
                l4[j] = (_Float16)(zr[j] - (float)h);
            }
            *(f16x4*)&Zh[zn * RS + zq * 4] = h4;
            *(f16x4*)&Zl[zn * RS + zq * 4] = l4;
        }
        if (kt < 15) {                 // T14: issue next-tile loads before compute
            wv0 = *(const float4*)(wsrc + (kt + 1) * 16);
            wv1 = *(const float4*)(wsrc + (kt + 1) * 16 + 4);
            #pragma unroll
            for (int j = 0; j < 4; ++j)
                zr[j] = zsrc[((size_t)(kt + 1) * 16 + j) * L_];
        }
        __syncthreads();

        f16x8 bh[2], bl[2];
        #pragma unroll
        for (int pt = 0; pt < 2; ++pt) {
            const int pr = (wp * 2 + pt) * 32 + col;
            bh[pt] = *(const f16x8*)&Zh[pr * RS + khl * 8];
            bl[pt] = *(const f16x8*)&Zl[pr * RS + khl * 8];
        }
        #pragma unroll
        for (int nt = 0; nt < 2; ++nt) {
            const int nr = (wn * 2 + nt) * 32 + col;
            f16x8 ah = *(const f16x8*)&Wh[nr * RS + khl * 8];
            f16x8 al = *(const f16x8*)&Wl[nr * RS + khl * 8];
            #pragma unroll
            for (int pt = 0; pt < 2; ++pt) {
                acc[nt][pt] = __builtin_amdgcn_mfma_f32_32x32x16_f16(ah, bh[pt], acc[nt][pt], 0, 0, 0);
                acc[nt][pt] = __builtin_amdgcn_mfma_f32_32x32x16_f16(ah, bl[pt], acc[nt][pt], 0, 0, 0);
                acc[nt][pt] = __builtin_amdgcn_mfma_f32_32x32x16_f16(al, bh[pt], acc[nt][pt], 0, 0, 0);
            }
        }
    }
    __syncthreads();                   // all frag reads done; LDS reusable

    // ---- epilogue: bias + gumbel + argmaxes + exp sums -----------------------
    float dmax[2] = {-INFINITY, -INFINITY}, smax[2] = {-INFINITY, -INFINITY};
    float S[2] = {0.f, 0.f}, T[2] = {0.f, 0.f};
    int didx[2] = {0x7fffffff, 0x7fffffff}, sidx[2] = {0x7fffffff, 0x7fffffff};
    const float* gb = gum + ((size_t)b * NE_ + nc0) * L_;
    const int p0 = pofs + (wp * 2) * 32 + col;
    const int p1 = p0 + 32;
    #pragma unroll
    for (int nt = 0; nt < 2; ++nt) {
        #pragma unroll
        for (int r = 0; r < 16; ++r) {
            // C/D layout: col = lane&31, row = (r&3) + 8*(r>>2) + 4*(lane>>5)
            const int nl = (wn * 2 + nt) * 32 + (r & 3) + 8 * (r >> 2) + 4 * khl;
            const int ng = nc0 + nl;
            const float pbv = pb[ng];
            const float l0 = acc[nt][0][r] + pbv;
            const float l1 = acc[nt][1][r] + pbv;
            if (l0 > dmax[0]) { dmax[0] = l0; didx[0] = ng; }   // nl ascending in-lane
            if (l1 > dmax[1]) { dmax[1] = l1; didx[1] = ng; }
            const float s0 = l0 + gb[(size_t)nl * L_ + p0];
            const float s1 = l1 + gb[(size_t)nl * L_ + p1];
            if (s0 > smax[0]) { smax[0] = s0; sidx[0] = ng; }
            if (s1 > smax[1]) { smax[1] = s1; sidx[1] = ng; }
            const float e0 = __expf(l0), e1 = __expf(l1);
            S[0] += e0; S[1] += e1;
            T[0] = fmaf(l0, e0, T[0]);
            T[1] = fmaf(l1, e1, T[1]);
        }
    }
    // lane ^ 32 combine (row-half): tie -> lower code index
    #pragma unroll
    for (int pt = 0; pt < 2; ++pt) {
        float ov; int oi;
        ov = __shfl_xor(dmax[pt], 32); oi = __shfl_xor(didx[pt], 32);
        if (ov > dmax[pt] || (ov == dmax[pt] && oi < didx[pt])) { dmax[pt] = ov; didx[pt] = oi; }
        ov = __shfl_xor(smax[pt], 32); oi = __shfl_xor(sidx[pt], 32);
        if (ov > smax[pt] || (ov == smax[pt] && oi < sidx[pt])) { smax[pt] = ov; sidx[pt] = oi; }
        S[pt] += __shfl_xor(S[pt], 32);
        T[pt] += __shfl_xor(T[pt], 32);
    }
    // cross-wave combine over wn (4 waves per wp group) via LDS [w][pt][6][32]
    float* ep = (float*)Wh;            // 12 KB, fits exactly
    if (lane < 32) {
        #pragma unroll
        for (int pt = 0; pt < 2; ++pt) {
            const int base = ((w * 2 + pt) * 6) * 32 + lane;
            ep[base + 0 * 32] = dmax[pt];
            ep[base + 1 * 32] = __int_as_float(didx[pt]);
            ep[base + 2 * 32] = smax[pt];
            ep[base + 3 * 32] = __int_as_float(sidx[pt]);
            ep[base + 4 * 32] = S[pt];
            ep[base + 5 * 32] = T[pt];
        }
    }
    __syncthreads();
    if (wn == 0 && lane < 32) {        // waves 0 and 4 merge their 3 partners
        #pragma unroll
        for (int pt = 0; pt < 2; ++pt) {
            #pragma unroll
            for (int d = 1; d < 4; ++d) {
                const int pbase = (((w + d) * 2 + pt) * 6) * 32 + lane;
                float ov = ep[pbase + 0 * 32]; int oi = __float_as_int(ep[pbase + 1 * 32]);
                if (ov > dmax[pt] || (ov == dmax[pt] && oi < didx[pt])) { dmax[pt] = ov; didx[pt] = oi; }
                ov = ep[pbase + 2 * 32]; oi = __float_as_int(ep[pbase + 3 * 32]);
                if (ov > smax[pt] || (ov == smax[pt] && oi < sidx[pt])) { smax[pt] = ov; sidx[pt] = oi; }
                S[pt] += ep[pbase + 4 * 32];
                T[pt] += ep[pbase + 5 * 32];
            }
            const int p = pofs + (wp * 2 + pt) * 32 + lane;
            const int gbase2 = (b * NCH + ch) * L_ + p;
            out[0 * STRIDE_P + gbase2] = dmax[pt];
            out[1 * STRIDE_P + gbase2] = __int_as_float(didx[pt]);
            out[2 * STRIDE_P + gbase2] = smax[pt];
            out[3 * STRIDE_P + gbase2] = __int_as_float(sidx[pt]);
            out[4 * STRIDE_P + gbase2] = S[pt];
            out[5 * STRIDE_P + gbase2] = T[pt];
        }
    }
    if (ch == 0 && psl == 0 && b == 0 && tid == 0) out[LOSS_IDX] = 0.f;
}

// ---------------- Kernel 2: combine chunks + mask + select + KL --------------
// grid (B, 8), block 256 = 32 p x 8 chunk-groups.
__global__ __launch_bounds__(256) void k2_combine(
    const float* __restrict__ noise, float* __restrict__ out)
{
    const int b = blockIdx.x, pg = blockIdx.y;
    const int t = threadIdx.x;
    const int pl = t & 31, cg = t >> 5;
    const int p = pg * 32 + pl;
    float dmax = -INFINITY, smax = -INFINITY, S = 0.f, T = 0.f;
    int didx = 0x7fffffff, sidx = 0x7fffffff;
    #pragma unroll
    for (int i = 0; i < 4; ++i) {
        const int ch = cg * 4 + i;
        const int base = (b * NCH + ch) * L_ + p;
        float dm = out[0 * STRIDE_P + base]; int di = __float_as_int(out[1 * STRIDE_P + base]);
        float sm = out[2 * STRIDE_P + base]; int si = __float_as_int(out[3 * STRIDE_P + base]);
        S += out[4 * STRIDE_P + base];
        T += out[5 * STRIDE_P + base];
        if (dm > dmax || (dm == dmax && di < didx)) { dmax = dm; didx = di; }
        if (sm > smax || (sm == smax && si < sidx)) { smax = sm; sidx = si; }
    }
    __shared__ float red[6][8][32];
    red[0][cg][pl] = dmax; red[1][cg][pl] = __int_as_float(didx);
    red[2][cg][pl] = smax; red[3][cg][pl] = __int_as_float(sidx);
    red[4][cg][pl] = S;    red[5][cg][pl] = T;
    for (int s = 4; s > 0; s >>= 1) {
        __syncthreads();
        if (cg < s) {
            float dm = red[0][cg + s][pl]; int di = __float_as_int(red[1][cg + s][pl]);
            float sm = red[2][cg + s][pl]; int si = __float_as_int(red[3][cg + s][pl]);
            if (dm > dmax || (dm == dmax && di < didx)) { dmax = dm; didx = di; }
            if (sm > smax || (sm == smax && si < sidx)) { smax = sm; sidx = si; }
            S += red[4][cg + s][pl]; T += red[5][cg + s][pl];
            red[0][cg][pl] = dmax; red[1][cg][pl] = __int_as_float(didx);
            red[2][cg][pl] = smax; red[3][cg][pl] = __int_as_float(sidx);
            red[4][cg][pl] = S;    red[5][cg][pl] = T;
        }
    }
    // rank of noise within row (stable argsort semantics)
    __shared__ float nz[256];
    nz[t] = noise[b * L_ + t];
    __syncthreads();
    const float myv = nz[p];
    int cnt = 0;
    #pragma unroll
    for (int jj = 0; jj < 32; ++jj) {
        const int j = cg * 32 + jj;
        const float v = nz[j];
        cnt += (v < myv) || (v == myv && j < p);
    }
    __shared__ int rc[8][32];
    rc[cg][pl] = cnt;
    for (int s = 4; s > 0; s >>= 1) {
        __syncthreads();
        if (cg < s) rc[cg][pl] += rc[cg + s][pl];
    }
    __syncthreads();
    if (cg == 0) {                     // threads 0..31 = lanes 0..31 of wave 0
        const int rank = rc[0][pl];
        const int sel = (rank >= 128) ? sidx : didx;   // mask=1 -> stochastic
        out[IND_BASE + b * L_ + p] = (float)sel;
        float kl = T / S - logf(S) + logf((float)NE_);
        #pragma unroll
        for (int m = 1; m < 32; m <<= 1) kl += __shfl_xor(kl, m);
        if (pl == 0) atomicAdd(&out[LOSS_IDX], (KLW / 4096.f) * kl);
    }
}

// ---------------- Kernel 3: z_q gather from codebook -------------------------
__global__ __launch_bounds__(256) void k3_gather(
    const float* __restrict__ emb, float* __restrict__ out)
{
    const int p = threadIdx.x;
    const int dc = blockIdx.x, b = blockIdx.y;
    const int sel = (int)out[IND_BASE + b * L_ + p];
    const float* er = emb + (size_t)sel * ED_ + dc * 8;
    const float4 e0 = *(const float4*)(er);
    const float4 e1 = *(const float4*)(er + 4);
    const size_t ob = ((size_t)b * ED_ + dc * 8) * L_ + p;
    out[ob + 0 * L_] = e0.x; out[ob + 1 * L_] = e0.y;
    out[ob + 2 * L_] = e0.z; out[ob + 3 * L_] = e0.w;
    out[ob + 4 * L_] = e1.x; out[ob + 5 * L_] = e1.y;
    out[ob + 6 * L_] = e1.z; out[ob + 7 * L_] = e1.w;
}

extern "C" void kernel_launch(void* const* d_in, const int* in_sizes, int n_in,
                              void* d_out, int out_size, void* d_ws, size_t ws_size,
                              hipStream_t stream) {
    const float* z     = (const float*)d_in[0];
    const float* pw    = (const float*)d_in[1];
    const float* pb    = (const float*)d_in[2];
    const float* emb   = (const float*)d_in[3];
    const float* gum   = (const float*)d_in[4];
    const float* noise = (const float*)d_in[5];
    float* out = (float*)d_out;

    hipLaunchKernelGGL(k1_mfma, dim3(NCH, 2, B_), dim3(512), 0, stream, z, pw, pb, gum, out);
    hipLaunchKernelGGL(k2_combine, dim3(B_, 8), dim3(256), 0, stream, noise, out);
    hipLaunchKernelGGL(k3_gather, dim3(32, B_), dim3(256), 0, stream, emb, out);
}